// Round 7
// baseline (692.742 us; speedup 1.0000x reference)
//
#include <hip/hip_runtime.h>
#include <hip/hip_fp16.h>
#include <math.h>

#define N_LEVELS 16
#define LOG2_T 19
#define TABLE_SIZE (1 << LOG2_T)
#define IDX_MASK ((unsigned)(TABLE_SIZE - 1))
#define THREADS 256
#define ITERS 8
#define PTS_PER_BLOCK (32 * ITERS)   // 8 lanes per point, 32 points per iter

typedef float f2_t __attribute__((ext_vector_type(2)));
typedef float f4_t __attribute__((ext_vector_type(4)));

struct ResTable { float r[N_LEVELS]; };

// ---- pass 1: fp16-compress ALL 16 tables into workspace (~20 us).
// Values in [-1e-4,1e-4]; fp16 abs err ~3e-8 (absmax unchanged rounds 1-6).
__global__ __launch_bounds__(256) void convert_all(
    const f2_t* __restrict__ emb, unsigned* __restrict__ tab, int n)
{
    int i = blockIdx.x * 256 + threadIdx.x;
    if (i >= n) return;
    f2_t e = __builtin_nontemporal_load(&emb[i]);
    union { __half2 h2; unsigned u; } c;
    c.h2 = __floats2half2_rn(e.x, e.y);
    __builtin_nontemporal_store(c.u, &tab[i]);
}

__device__ __forceinline__ unsigned pick4(uint4 g, unsigned s)
{
    unsigned t0 = (s & 1u) ? g.y : g.x;
    unsigned t1 = (s & 1u) ? g.w : g.z;
    return (s & 2u) ? t1 : t0;
}

__device__ __forceinline__ void acc_corner(
    unsigned w0, unsigned w1, float g0, float g1, float& a0, float& a1)
{
    union { unsigned u; __half2 h; } p0, p1;
    p0.u = w0; p1.u = w1;
    a0 += g0 * __low2float(p0.h)  + g1 * __low2float(p1.h);
    a1 += g0 * __high2float(p0.h) + g1 * __high2float(p1.h);
}

// Both levels of one lane's pair, single uniform path (no role divergence).
// Address setup + ALL 8 group loads issued before any extraction math (MLP).
// mod-4 16B groups: x-prime==1 so i1=(ux+1)^h stays in i0's aligned 4-group
// unless ux%4==3 (bit-carry leaves the group) -> 25% patch rate.
__device__ __forceinline__ void eval2(
    float gridA, float gridB,
    const unsigned* __restrict__ tA, const unsigned* __restrict__ tB,
    float xx, float xy, float xz,
    float& o0, float& o1, float& o2, float& o3)
{
    // ---- weight/index setup: EXACT fp32 op sequence of the verified
    // baseline (add, div, floor; no FMA contraction of the vmin term).
    float txA = (xx + 1.0f) / gridA;
    float tyA = (xy + 1.0f) / gridA;
    float tzA = (xz + 1.0f) / gridA;
    int blxA = (int)floorf(txA);
    int blyA = (int)floorf(tyA);
    int blzA = (int)floorf(tzA);
    float wxA = (xx - ((float)blxA * gridA + -1.0f)) / gridA;
    float wyA = (xy - ((float)blyA * gridA + -1.0f)) / gridA;
    float wzA = (xz - ((float)blzA * gridA + -1.0f)) / gridA;

    float txB = (xx + 1.0f) / gridB;
    float tyB = (xy + 1.0f) / gridB;
    float tzB = (xz + 1.0f) / gridB;
    int blxB = (int)floorf(txB);
    int blyB = (int)floorf(tyB);
    int blzB = (int)floorf(tzB);
    float wxB = (xx - ((float)blxB * gridB + -1.0f)) / gridB;
    float wyB = (xy - ((float)blyB * gridB + -1.0f)) / gridB;
    float wzB = (xz - ((float)blzB * gridB + -1.0f)) / gridB;

    unsigned uxA = (unsigned)blxA, uxB = (unsigned)blxB;
    unsigned hy0A = (unsigned)blyA * 2654435761u;
    unsigned hy1A = ((unsigned)blyA + 1u) * 2654435761u;
    unsigned hz0A = (unsigned)blzA * 805459861u;
    unsigned hz1A = ((unsigned)blzA + 1u) * 805459861u;
    unsigned hy0B = (unsigned)blyB * 2654435761u;
    unsigned hy1B = ((unsigned)blyB + 1u) * 2654435761u;
    unsigned hz0B = (unsigned)blzB * 805459861u;
    unsigned hz1B = ((unsigned)blzB + 1u) * 805459861u;

    unsigned i0A[4], i1A[4], i0B[4], i1B[4];
#pragma unroll
    for (int yz = 0; yz < 4; ++yz) {
        unsigned hA = ((yz & 2) ? hy1A : hy0A) ^ ((yz & 1) ? hz1A : hz0A);
        unsigned hB = ((yz & 2) ? hy1B : hy0B) ^ ((yz & 1) ? hz1B : hz0B);
        i0A[yz] = (uxA ^ hA) & IDX_MASK;
        i1A[yz] = ((uxA + 1u) ^ hA) & IDX_MASK;
        i0B[yz] = (uxB ^ hB) & IDX_MASK;
        i1B[yz] = ((uxB + 1u) ^ hB) & IDX_MASK;
    }

    // ---- issue all 8 group loads back-to-back
    uint4 gA[4], gB[4];
#pragma unroll
    for (int yz = 0; yz < 4; ++yz) gA[yz] = *(const uint4*)(tA + (i0A[yz] & ~3u));
#pragma unroll
    for (int yz = 0; yz < 4; ++yz) gB[yz] = *(const uint4*)(tB + (i0B[yz] & ~3u));

    // ---- extract; patch the straddling x+1 corners (~25% of lanes each)
    unsigned w0A[4], w1A[4], w0B[4], w1B[4];
#pragma unroll
    for (int yz = 0; yz < 4; ++yz) {
        w0A[yz] = pick4(gA[yz], i0A[yz] & 3u);
        w1A[yz] = pick4(gA[yz], i1A[yz] & 3u);
        w0B[yz] = pick4(gB[yz], i0B[yz] & 3u);
        w1B[yz] = pick4(gB[yz], i1B[yz] & 3u);
    }
    if ((uxA & 3u) == 3u) {
#pragma unroll
        for (int yz = 0; yz < 4; ++yz) w1A[yz] = tA[i1A[yz]];
    }
    if ((uxB & 3u) == 3u) {
#pragma unroll
        for (int yz = 0; yz < 4; ++yz) w1B[yz] = tB[i1B[yz]];
    }

    // ---- trilinear accumulate (yz bit order: by=yz>>1, bz=yz&1)
    float fyA[2] = {1.0f - wyA, wyA}, fzA[2] = {1.0f - wzA, wzA};
    float fyB[2] = {1.0f - wyB, wyB}, fzB[2] = {1.0f - wzB, wzB};
    float fx0A = 1.0f - wxA, fx1A = wxA;
    float fx0B = 1.0f - wxB, fx1B = wxB;
    o0 = 0.0f; o1 = 0.0f; o2 = 0.0f; o3 = 0.0f;
#pragma unroll
    for (int yz = 0; yz < 4; ++yz) {
        float wA = fyA[yz >> 1] * fzA[yz & 1];
        float wB = fyB[yz >> 1] * fzB[yz & 1];
        acc_corner(w0A[yz], w1A[yz], fx0A * wA, fx1A * wA, o0, o1);
        acc_corner(w0B[yz], w1B[yz], fx0B * wB, fx1B * wB, o2, o3);
    }
}

// ---- pass 2: thread t -> (point t>>3, level-pair t&7). Uniform path for all
// lanes (coarse levels hash like fine ones -- hit tier is irrelevant, request
// count is what we pay for). Stores are lane-consecutive 16B -> coalesced.
__global__ __launch_bounds__(256) void ingp_hash_v7(
    const float* __restrict__ x,
    const unsigned* __restrict__ tabAll,
    float* __restrict__ out,
    int n_pts,
    ResTable res)
{
    int lp  = threadIdx.x & 7;
    int ptl = threadIdx.x >> 3;

    // per-lane level constants via constant-index select chain (no divergent
    // kernarg-array index -> no scratch)
    float rA = res.r[0], rB = res.r[1];
#pragma unroll
    for (int k = 1; k < 8; ++k) {
        if (lp == k) { rA = res.r[2 * k]; rB = res.r[2 * k + 1]; }
    }
    float gridA = 2.0f / rA;     // fp32 IEEE div == numpy
    float gridB = 2.0f / rB;
    const unsigned* tA = tabAll + (size_t)(2 * lp) * TABLE_SIZE;
    const unsigned* tB = tA + TABLE_SIZE;

    int base_n = blockIdx.x * PTS_PER_BLOCK + ptl;

#pragma unroll 1
    for (int it = 0; it < ITERS; ++it) {
        int n = base_n + it * 32;
        int nc = n < n_pts ? n : n_pts - 1;
        float xx = fminf(fmaxf(__builtin_nontemporal_load(&x[nc * 3 + 0]), -1.0f), 1.0f);
        float xy = fminf(fmaxf(__builtin_nontemporal_load(&x[nc * 3 + 1]), -1.0f), 1.0f);
        float xz = fminf(fmaxf(__builtin_nontemporal_load(&x[nc * 3 + 2]), -1.0f), 1.0f);

        float r0, r1, r2, r3;
        eval2(gridA, gridB, tA, tB, xx, xy, xz, r0, r1, r2, r3);

        if (n < n_pts) {
            f4_t o4 = {r0, r1, r2, r3};
            __builtin_nontemporal_store(
                o4, (f4_t*)(out + (size_t)n * (N_LEVELS * 2) + lp * 4));
        }
    }
}

// ---- fallback (ws unavailable): round-3 proven f32 pair kernel.
__global__ __launch_bounds__(256) void ingp_hash_pair_f32(
    const float* __restrict__ x, const f2_t* __restrict__ emb,
    float* __restrict__ out, int n_pts, ResTable res)
{
    int b = blockIdx.x;
    int slot = b & 7;
    int n = (b >> 3) * 256 + (int)threadIdx.x;
    if (n >= n_pts) return;
    float xx = fminf(fmaxf(x[n * 3 + 0], -1.0f), 1.0f);
    float xy = fminf(fmaxf(x[n * 3 + 1], -1.0f), 1.0f);
    float xz = fminf(fmaxf(x[n * 3 + 2], -1.0f), 1.0f);
    float r0 = 0.f, r1 = 0.f, r2 = 0.f, r3 = 0.f;
#pragma unroll
    for (int hl = 0; hl < 2; ++hl) {
        int lev = 2 * slot + hl;
        float grid = 2.0f / res.r[lev];
        int blx = (int)floorf((xx + 1.0f) / grid);
        int bly = (int)floorf((xy + 1.0f) / grid);
        int blz = (int)floorf((xz + 1.0f) / grid);
        float wx = (xx - ((float)blx * grid + -1.0f)) / grid;
        float wy = (xy - ((float)bly * grid + -1.0f)) / grid;
        float wz = (xz - ((float)blz * grid + -1.0f)) / grid;
        const f2_t* tab = emb + (size_t)lev * TABLE_SIZE;
        float acc0 = 0.0f, acc1 = 0.0f;
#pragma unroll
        for (int k = 0; k < 8; ++k) {
            int bx = (k >> 2) & 1, by = (k >> 1) & 1, bz = k & 1;
            unsigned h = ((unsigned)(blx + bx)
                          ^ ((unsigned)(bly + by) * 2654435761u)
                          ^ ((unsigned)(blz + bz) * 805459861u)) & IDX_MASK;
            f2_t e = tab[h];
            float w = (bx ? wx : 1.0f - wx) * (by ? wy : 1.0f - wy) * (bz ? wz : 1.0f - wz);
            acc0 += w * e.x; acc1 += w * e.y;
        }
        if (hl == 0) { r0 = acc0; r1 = acc1; } else { r2 = acc0; r3 = acc1; }
    }
    f4_t o4 = {r0, r1, r2, r3};
    __builtin_nontemporal_store(o4, (f4_t*)(out + (size_t)n * (N_LEVELS * 2) + slot * 4));
}

extern "C" void kernel_launch(void* const* d_in, const int* in_sizes, int n_in,
                              void* d_out, int out_size, void* d_ws, size_t ws_size,
                              hipStream_t stream) {
    const float* x   = (const float*)d_in[0];
    const float* emb = (const float*)d_in[1];
    float* out = (float*)d_out;
    int n_pts = in_sizes[0] / 3;

    // RESOLUTIONS: numpy float64 semantics on host (same libm as np)
    ResTable res;
    double b = exp((log(512.0) - log(16.0)) / 15.0);
    for (int i = 0; i < N_LEVELS; ++i)
        res.r[i] = (float)floor(16.0 * pow(b, (double)i));

    size_t need = (size_t)N_LEVELS * TABLE_SIZE * sizeof(unsigned);  // 32 MB fp16
    if (ws_size >= need && d_ws != nullptr) {
        unsigned* tabAll = (unsigned*)d_ws;
        int n_entries = N_LEVELS * TABLE_SIZE;
        hipLaunchKernelGGL(convert_all,
                           dim3((n_entries + 255) / 256), dim3(256), 0, stream,
                           (const f2_t*)emb, tabAll, n_entries);
        int blocks = (n_pts + PTS_PER_BLOCK - 1) / PTS_PER_BLOCK;
        hipLaunchKernelGGL(ingp_hash_v7, dim3(blocks), dim3(256), 0, stream,
                           x, tabAll, out, n_pts, res);
    } else {
        int blocks = 8 * ((n_pts + 255) / 256);
        hipLaunchKernelGGL(ingp_hash_pair_f32, dim3(blocks), dim3(256), 0, stream,
                           x, (const f2_t*)emb, out, n_pts, res);
    }
}

// Round 8
// 603.861 us; speedup vs baseline: 1.1472x; 1.1472x over previous
//
#include <hip/hip_runtime.h>
#include <hip/hip_fp16.h>
#include <math.h>

#define N_LEVELS 16
#define LOG2_T 19
#define TABLE_SIZE (1 << LOG2_T)
#define IDX_MASK ((unsigned)(TABLE_SIZE - 1))
#define N_STAGED 3                  // L0..L2 dense in LDS
#define N_LDS 6104                  // 1000 + 1728 + 3375 (+1 pad) entries = 24.4 KB
#define THREADS 256
#define PTS_PER_THREAD 2
#define PTS_PER_BLOCK (THREADS * PTS_PER_THREAD)

typedef float f2_t __attribute__((ext_vector_type(2)));
typedef float f4_t __attribute__((ext_vector_type(4)));

struct Params {
    float res[N_LEVELS];
    int   c0[N_STAGED];
    int   K[N_STAGED];
    int   K2[N_STAGED];
    int   base[N_STAGED + 1];   // 4-entry-padded prefix offsets into dense region
    int   n_pts;
};

// ---- pass 1a: fp16-compress ALL 16 tables into workspace (~25 us).
// Values in [-1e-4,1e-4]; fp16 abs err ~3e-8 (absmax unchanged rounds 1-7).
__global__ __launch_bounds__(256) void convert_all(
    const f2_t* __restrict__ emb, unsigned* __restrict__ tab, int n)
{
    int i = blockIdx.x * 256 + threadIdx.x;
    if (i >= n) return;
    f2_t e = __builtin_nontemporal_load(&emb[i]);
    union { __half2 h2; unsigned u; } c;
    c.h2 = __floats2half2_rn(e.x, e.y);
    __builtin_nontemporal_store(c.u, &tab[i]);
}

// ---- pass 1b: dense re-indexed coarse tables (L0..L2), fp16. (R4-proven.)
__global__ __launch_bounds__(256) void build_dense(
    const f2_t* __restrict__ emb, unsigned* __restrict__ dense, Params P)
{
    int t = blockIdx.x * 256 + threadIdx.x;
    if (t >= P.base[N_STAGED]) return;
    int lev = 2;
    if (t < P.base[2]) lev = 1;
    if (t < P.base[1]) lev = 0;
    int li = t - P.base[lev];
    int K  = P.K[lev];
    if (li >= K * K * K) return;               // padding slot
    int kx = li % K; int r2 = li / K; int ky = r2 % K; int kz = r2 / K;
    unsigned cx = (unsigned)(P.c0[lev] + kx);
    unsigned cy = (unsigned)(P.c0[lev] + ky);
    unsigned cz = (unsigned)(P.c0[lev] + kz);
    unsigned h = (cx ^ (cy * 2654435761u) ^ (cz * 805459861u)) & IDX_MASK;
    f2_t e = emb[(size_t)lev * TABLE_SIZE + h];
    union { __half2 h2; unsigned u; } c;
    c.h2 = __floats2half2_rn(e.x, e.y);
    dense[t] = c.u;
}

__device__ __forceinline__ unsigned pick4(uint4 g, unsigned s)
{
    unsigned t0 = (s & 1u) ? g.y : g.x;
    unsigned t1 = (s & 1u) ? g.w : g.z;
    return (s & 2u) ? t1 : t0;
}

__device__ __forceinline__ void acc_corner(
    unsigned w0, unsigned w1, float g0, float g1, float& a0, float& a1)
{
    union { unsigned u; __half2 h; } p0, p1;
    p0.u = w0; p1.u = w1;
    a0 += g0 * __low2float(p0.h)  + g1 * __low2float(p1.h);
    a1 += g0 * __high2float(p0.h) + g1 * __high2float(p1.h);
}

// EXACT fp32 op sequence of the verified baseline (add, div, floor; no FMA
// contraction of the vmin term).
#define GRID_SETUP(gridv)                                                  \
    float tx = (xx + 1.0f) / (gridv);                                      \
    float ty = (xy + 1.0f) / (gridv);                                      \
    float tz = (xz + 1.0f) / (gridv);                                      \
    int blx = (int)floorf(tx);                                             \
    int bly = (int)floorf(ty);                                             \
    int blz = (int)floorf(tz);                                             \
    float wx = (xx - ((float)blx * (gridv) + -1.0f)) / (gridv);            \
    float wy = (xy - ((float)bly * (gridv) + -1.0f)) / (gridv);            \
    float wz = (xz - ((float)blz * (gridv) + -1.0f)) / (gridv);            \
    float fy[2] = {1.0f - wy, wy};                                         \
    float fz[2] = {1.0f - wz, wz};                                         \
    float fx0 = 1.0f - wx, fx1 = wx;

// Hashed fp16 level (R7-proven numerics): mod-4 16B group gathers; x-prime==1
// so the x-pair shares the aligned 4-group unless blx%4==3 (~25% patch).
__device__ __forceinline__ void eval_hash(
    float grid, const unsigned* __restrict__ tab,
    float xx, float xy, float xz, float& a0, float& a1)
{
    GRID_SETUP(grid)
    unsigned ux  = (unsigned)blx;
    unsigned hy0 = (unsigned)bly * 2654435761u;
    unsigned hy1 = ((unsigned)bly + 1u) * 2654435761u;
    unsigned hz0 = (unsigned)blz * 805459861u;
    unsigned hz1 = ((unsigned)blz + 1u) * 805459861u;
    unsigned i0a[4], i1a[4];
#pragma unroll
    for (int yz = 0; yz < 4; ++yz) {
        unsigned hyz = ((yz & 2) ? hy1 : hy0) ^ ((yz & 1) ? hz1 : hz0);
        i0a[yz] = (ux ^ hyz) & IDX_MASK;
        i1a[yz] = ((ux + 1u) ^ hyz) & IDX_MASK;
    }
    uint4 g[4];
#pragma unroll
    for (int yz = 0; yz < 4; ++yz) g[yz] = *(const uint4*)(tab + (i0a[yz] & ~3u));
    unsigned w0a[4], w1a[4];
#pragma unroll
    for (int yz = 0; yz < 4; ++yz) {
        w0a[yz] = pick4(g[yz], i0a[yz] & 3u);
        w1a[yz] = pick4(g[yz], i1a[yz] & 3u);          // bogus iff ux%4==3
    }
    if ((ux & 3u) == 3u) {                             // ~25% of lanes
#pragma unroll
        for (int yz = 0; yz < 4; ++yz) w1a[yz] = tab[i1a[yz]];
    }
    a0 = 0.0f; a1 = 0.0f;
#pragma unroll
    for (int yz = 0; yz < 4; ++yz) {
        float wyz = fy[yz >> 1] * fz[yz & 1];
        acc_corner(w0a[yz], w1a[yz], fx0 * wyz, fx1 * wyz, a0, a1);
    }
}

// LDS dense coarse level (R4-proven): x-neighbors adjacent -> ds_read2 pair.
template <int LEV>
__device__ __forceinline__ void eval_lds(
    const Params& P, const unsigned* s_dense, const f2_t* __restrict__ emb,
    float xx, float xy, float xz, float& a0, float& a1)
{
    float grid = 2.0f / P.res[LEV];
    GRID_SETUP(grid)
    int K = P.K[LEV], K2 = P.K2[LEV];
    int kx = blx - P.c0[LEV], ky = bly - P.c0[LEV], kz = blz - P.c0[LEV];
    a0 = 0.0f; a1 = 0.0f;
    unsigned lim = (unsigned)(K - 1);
    if ((unsigned)kx < lim && (unsigned)ky < lim && (unsigned)kz < lim) {
        int ib = P.base[LEV] + (kz * K + ky) * K + kx;
#pragma unroll
        for (int yz = 0; yz < 4; ++yz) {
            int id = ib + (yz >> 1) * K + (yz & 1) * K2;
            float wyz = fy[yz >> 1] * fz[yz & 1];
            acc_corner(s_dense[id], s_dense[id + 1], fx0 * wyz, fx1 * wyz,
                       a0, a1);
        }
    } else {
        // cold safety fallback: exact f32 hash gathers (corner outside box)
        const f2_t* tab = emb + (size_t)LEV * TABLE_SIZE;
#pragma unroll
        for (int k = 0; k < 8; ++k) {
            int bx = (k >> 2) & 1, by = (k >> 1) & 1, bz = k & 1;
            unsigned h = ((unsigned)(blx + bx)
                          ^ ((unsigned)(bly + by) * 2654435761u)
                          ^ ((unsigned)(blz + bz) * 805459861u)) & IDX_MASK;
            f2_t e = tab[h];
            float w = (bx ? wx : 1.0f - wx) * fy[by] * fz[bz];
            a0 += w * e.x; a1 += w * e.y;
        }
    }
}

// ---- pass 2: thread = point, all 16 levels serial (uniform path, zero role
// divergence -- R4 structure at R7-class occupancy: LDS cut to 24.4 KB).
__global__ __launch_bounds__(256) void ingp_hash_v8(
    const float* __restrict__ x,
    const unsigned* __restrict__ tabAll,
    const unsigned* __restrict__ denseG,
    const f2_t* __restrict__ emb,
    float* __restrict__ out,
    Params P)
{
    __shared__ __align__(16) unsigned s_dense[N_LDS];
    {
        const uint4* src = (const uint4*)denseG;
        uint4* dst = (uint4*)s_dense;
        for (int id = threadIdx.x; id < N_LDS / 4; id += THREADS)
            dst[id] = src[id];
    }
    __syncthreads();

    int base_pt = blockIdx.x * PTS_PER_BLOCK;
#pragma unroll 1
    for (int j = 0; j < PTS_PER_THREAD; ++j) {
        int n = base_pt + j * THREADS + (int)threadIdx.x;
        if (n >= P.n_pts) continue;            // no syncs below: safe

        // one 16B x load (3 used floats; last point falls back to scalars)
        float xx, xy, xz;
        if (n < P.n_pts - 1) {
            f4_t v;
            __builtin_memcpy(&v, x + 3 * (size_t)n, 16);
            xx = v.x; xy = v.y; xz = v.z;
        } else {
            xx = x[3 * (size_t)n]; xy = x[3 * (size_t)n + 1]; xz = x[3 * (size_t)n + 2];
        }
        xx = fminf(fmaxf(xx, -1.0f), 1.0f);
        xy = fminf(fmaxf(xy, -1.0f), 1.0f);
        xz = fminf(fmaxf(xz, -1.0f), 1.0f);

        float* orow = out + (size_t)n * (N_LEVELS * 2);
        float a0, a1, b0, b1;

        // pair 0: L0, L1 from LDS
        eval_lds<0>(P, s_dense, emb, xx, xy, xz, a0, a1);
        eval_lds<1>(P, s_dense, emb, xx, xy, xz, b0, b1);
        { f4_t o = {a0, a1, b0, b1};
          __builtin_nontemporal_store(o, (f4_t*)(orow + 0)); }

        // pair 1: L2 from LDS, L3 hashed
        eval_lds<2>(P, s_dense, emb, xx, xy, xz, a0, a1);
        eval_hash(2.0f / P.res[3], tabAll + (size_t)3 * TABLE_SIZE,
                  xx, xy, xz, b0, b1);
        { f4_t o = {a0, a1, b0, b1};
          __builtin_nontemporal_store(o, (f4_t*)(orow + 4)); }

        // pairs 2..7: L4..L15 hashed
#pragma unroll
        for (int p = 2; p < 8; ++p) {
            eval_hash(2.0f / P.res[2 * p], tabAll + (size_t)(2 * p) * TABLE_SIZE,
                      xx, xy, xz, a0, a1);
            eval_hash(2.0f / P.res[2 * p + 1], tabAll + (size_t)(2 * p + 1) * TABLE_SIZE,
                      xx, xy, xz, b0, b1);
            f4_t o = {a0, a1, b0, b1};
            __builtin_nontemporal_store(o, (f4_t*)(orow + p * 4));
        }
    }
}

// ---- fallback (ws unavailable): round-3 proven f32 pair kernel.
__global__ __launch_bounds__(256) void ingp_hash_pair_f32(
    const float* __restrict__ x, const f2_t* __restrict__ emb,
    float* __restrict__ out, int n_pts, Params P)
{
    int b = blockIdx.x;
    int slot = b & 7;
    int n = (b >> 3) * 256 + (int)threadIdx.x;
    if (n >= n_pts) return;
    float xx = fminf(fmaxf(x[n * 3 + 0], -1.0f), 1.0f);
    float xy = fminf(fmaxf(x[n * 3 + 1], -1.0f), 1.0f);
    float xz = fminf(fmaxf(x[n * 3 + 2], -1.0f), 1.0f);
    float r0 = 0.f, r1 = 0.f, r2 = 0.f, r3 = 0.f;
#pragma unroll
    for (int hl = 0; hl < 2; ++hl) {
        int lev = 2 * slot + hl;
        float grid = 2.0f / P.res[lev];
        int blx = (int)floorf((xx + 1.0f) / grid);
        int bly = (int)floorf((xy + 1.0f) / grid);
        int blz = (int)floorf((xz + 1.0f) / grid);
        float wx = (xx - ((float)blx * grid + -1.0f)) / grid;
        float wy = (xy - ((float)bly * grid + -1.0f)) / grid;
        float wz = (xz - ((float)blz * grid + -1.0f)) / grid;
        const f2_t* tab = emb + (size_t)lev * TABLE_SIZE;
        float acc0 = 0.0f, acc1 = 0.0f;
#pragma unroll
        for (int k = 0; k < 8; ++k) {
            int bx = (k >> 2) & 1, by = (k >> 1) & 1, bz = k & 1;
            unsigned h = ((unsigned)(blx + bx)
                          ^ ((unsigned)(bly + by) * 2654435761u)
                          ^ ((unsigned)(blz + bz) * 805459861u)) & IDX_MASK;
            f2_t e = tab[h];
            float w = (bx ? wx : 1.0f - wx) * (by ? wy : 1.0f - wy) * (bz ? wz : 1.0f - wz);
            acc0 += w * e.x; acc1 += w * e.y;
        }
        if (hl == 0) { r0 = acc0; r1 = acc1; } else { r2 = acc0; r3 = acc1; }
    }
    f4_t o4 = {r0, r1, r2, r3};
    __builtin_nontemporal_store(o4, (f4_t*)(out + (size_t)n * (N_LEVELS * 2) + slot * 4));
}

extern "C" void kernel_launch(void* const* d_in, const int* in_sizes, int n_in,
                              void* d_out, int out_size, void* d_ws, size_t ws_size,
                              hipStream_t stream) {
    const float* x   = (const float*)d_in[0];
    const float* emb = (const float*)d_in[1];
    float* out = (float*)d_out;
    int n_pts = in_sizes[0] / 3;

    Params P;
    // RESOLUTIONS: numpy float64 semantics on host (same libm as np)
    double b = exp((log(512.0) - log(16.0)) / 15.0);
    for (int i = 0; i < N_LEVELS; ++i)
        P.res[i] = (float)floor(16.0 * pow(b, (double)i));
    P.n_pts = n_pts;

    // Dense box bounds with the SAME fp32 ops the device uses (x in [0,1]).
    int base = 0;
    for (int l = 0; l < N_STAGED; ++l) {
        float grid = 2.0f / P.res[l];
        int blmin = (int)floorf(1.0f / grid);
        int blmax = (int)floorf(2.0f / grid);
        int K = blmax - blmin + 2;
        P.c0[l] = blmin; P.K[l] = K; P.K2[l] = K * K;
        P.base[l] = base;
        base += K * K * K;
        base = (base + 3) & ~3;        // 4-entry align each segment
    }
    P.base[N_STAGED] = base;

    size_t need = (size_t)N_LEVELS * TABLE_SIZE * 4 + (size_t)N_LDS * 4;
    bool ok = (base == N_LDS) && (ws_size >= need) && (d_ws != nullptr);
    if (ok) {
        unsigned* tabAll = (unsigned*)d_ws;
        unsigned* denseG = tabAll + (size_t)N_LEVELS * TABLE_SIZE;
        int nAll = N_LEVELS * TABLE_SIZE;
        hipLaunchKernelGGL(convert_all, dim3((nAll + 255) / 256), dim3(256), 0, stream,
                           (const f2_t*)emb, tabAll, nAll);
        hipLaunchKernelGGL(build_dense, dim3((base + 255) / 256), dim3(256), 0, stream,
                           (const f2_t*)emb, denseG, P);
        int blocks = (n_pts + PTS_PER_BLOCK - 1) / PTS_PER_BLOCK;
        hipLaunchKernelGGL(ingp_hash_v8, dim3(blocks), dim3(256), 0, stream,
                           x, tabAll, denseG, (const f2_t*)emb, out, P);
    } else {
        int blocks = 8 * ((n_pts + 255) / 256);
        hipLaunchKernelGGL(ingp_hash_pair_f32, dim3(blocks), dim3(256), 0, stream,
                           x, (const f2_t*)emb, out, n_pts, P);
    }
}

// Round 9
// 589.324 us; speedup vs baseline: 1.1755x; 1.0247x over previous
//
#include <hip/hip_runtime.h>
#include <hip/hip_fp16.h>
#include <math.h>

#define N_LEVELS 16
#define LOG2_T 19
#define TABLE_SIZE (1 << LOG2_T)
#define IDX_MASK ((unsigned)(TABLE_SIZE - 1))
#define N_STAGED 2                  // L0..L1 dense in LDS
#define N_LDS 2728                  // 1000 + 1728 entries = 10.9 KB
#define THREADS 256
#define GRID_BLOCKS 2048            // 8 blocks/CU x 256 CU: zero quantization tail

typedef float f2_t __attribute__((ext_vector_type(2)));
typedef float f4_t __attribute__((ext_vector_type(4)));

struct Params {
    float res[N_LEVELS];
    int   c0[N_STAGED];
    int   K[N_STAGED];
    int   K2[N_STAGED];
    int   base[N_STAGED + 1];
    int   n_pts;
};

// ---- pass 1a: fp16-compress ALL 16 tables into workspace (~25 us).
// Values in [-1e-4,1e-4]; fp16 abs err ~3e-8 (absmax unchanged rounds 1-8).
__global__ __launch_bounds__(256) void convert_all(
    const f2_t* __restrict__ emb, unsigned* __restrict__ tab, int n)
{
    int i = blockIdx.x * 256 + threadIdx.x;
    if (i >= n) return;
    f2_t e = __builtin_nontemporal_load(&emb[i]);
    union { __half2 h2; unsigned u; } c;
    c.h2 = __floats2half2_rn(e.x, e.y);
    __builtin_nontemporal_store(c.u, &tab[i]);
}

// ---- pass 1b: dense re-indexed coarse tables (L0..L1), fp16. (R4/R8-proven.)
__global__ __launch_bounds__(256) void build_dense(
    const f2_t* __restrict__ emb, unsigned* __restrict__ dense, Params P)
{
    int t = blockIdx.x * 256 + threadIdx.x;
    if (t >= P.base[N_STAGED]) return;
    int lev = (t >= P.base[1]) ? 1 : 0;
    int li = t - P.base[lev];
    int K  = P.K[lev];
    if (li >= K * K * K) return;               // padding slot
    int kx = li % K; int r2 = li / K; int ky = r2 % K; int kz = r2 / K;
    unsigned cx = (unsigned)(P.c0[lev] + kx);
    unsigned cy = (unsigned)(P.c0[lev] + ky);
    unsigned cz = (unsigned)(P.c0[lev] + kz);
    unsigned h = (cx ^ (cy * 2654435761u) ^ (cz * 805459861u)) & IDX_MASK;
    f2_t e = emb[(size_t)lev * TABLE_SIZE + h];
    union { __half2 h2; unsigned u; } c;
    c.h2 = __floats2half2_rn(e.x, e.y);
    dense[t] = c.u;
}

__device__ __forceinline__ unsigned pick4(uint4 g, unsigned s)
{
    unsigned t0 = (s & 1u) ? g.y : g.x;
    unsigned t1 = (s & 1u) ? g.w : g.z;
    return (s & 2u) ? t1 : t0;
}

__device__ __forceinline__ void acc_corner(
    unsigned w0, unsigned w1, float g0, float g1, float& a0, float& a1)
{
    union { unsigned u; __half2 h; } p0, p1;
    p0.u = w0; p1.u = w1;
    a0 += g0 * __low2float(p0.h)  + g1 * __low2float(p1.h);
    a1 += g0 * __high2float(p0.h) + g1 * __high2float(p1.h);
}

// EXACT fp32 op sequence of the verified baseline (add, div, floor; no FMA
// contraction of the vmin term).
#define GRID_SETUP(gridv)                                                  \
    float tx = (xx + 1.0f) / (gridv);                                      \
    float ty = (xy + 1.0f) / (gridv);                                      \
    float tz = (xz + 1.0f) / (gridv);                                      \
    int blx = (int)floorf(tx);                                             \
    int bly = (int)floorf(ty);                                             \
    int blz = (int)floorf(tz);                                             \
    float wx = (xx - ((float)blx * (gridv) + -1.0f)) / (gridv);            \
    float wy = (xy - ((float)bly * (gridv) + -1.0f)) / (gridv);            \
    float wz = (xz - ((float)blz * (gridv) + -1.0f)) / (gridv);            \
    float fy[2] = {1.0f - wy, wy};                                         \
    float fz[2] = {1.0f - wz, wz};                                         \
    float fx0 = 1.0f - wx, fx1 = wx;

// Hashed fp16 level (R7/R8-proven): mod-4 16B group gathers; x-prime==1 so
// the x-pair shares the aligned 4-group unless blx%4==3 (~25% patch).
__device__ __forceinline__ void eval_hash(
    float grid, const unsigned* __restrict__ tab,
    float xx, float xy, float xz, float& a0, float& a1)
{
    GRID_SETUP(grid)
    unsigned ux  = (unsigned)blx;
    unsigned hy0 = (unsigned)bly * 2654435761u;
    unsigned hy1 = ((unsigned)bly + 1u) * 2654435761u;
    unsigned hz0 = (unsigned)blz * 805459861u;
    unsigned hz1 = ((unsigned)blz + 1u) * 805459861u;
    unsigned i0a[4], i1a[4];
#pragma unroll
    for (int yz = 0; yz < 4; ++yz) {
        unsigned hyz = ((yz & 2) ? hy1 : hy0) ^ ((yz & 1) ? hz1 : hz0);
        i0a[yz] = (ux ^ hyz) & IDX_MASK;
        i1a[yz] = ((ux + 1u) ^ hyz) & IDX_MASK;
    }
    uint4 g[4];
#pragma unroll
    for (int yz = 0; yz < 4; ++yz) g[yz] = *(const uint4*)(tab + (i0a[yz] & ~3u));
    unsigned w0a[4], w1a[4];
#pragma unroll
    for (int yz = 0; yz < 4; ++yz) {
        w0a[yz] = pick4(g[yz], i0a[yz] & 3u);
        w1a[yz] = pick4(g[yz], i1a[yz] & 3u);          // bogus iff ux%4==3
    }
    if ((ux & 3u) == 3u) {                             // ~25% of lanes
#pragma unroll
        for (int yz = 0; yz < 4; ++yz) w1a[yz] = tab[i1a[yz]];
    }
    a0 = 0.0f; a1 = 0.0f;
#pragma unroll
    for (int yz = 0; yz < 4; ++yz) {
        float wyz = fy[yz >> 1] * fz[yz & 1];
        acc_corner(w0a[yz], w1a[yz], fx0 * wyz, fx1 * wyz, a0, a1);
    }
}

// LDS dense coarse level (R4/R8-proven): x-neighbors adjacent in dense layout.
template <int LEV>
__device__ __forceinline__ void eval_lds(
    const Params& P, const unsigned* s_dense, const f2_t* __restrict__ emb,
    float xx, float xy, float xz, float& a0, float& a1)
{
    float grid = 2.0f / P.res[LEV];
    GRID_SETUP(grid)
    int K = P.K[LEV], K2 = P.K2[LEV];
    int kx = blx - P.c0[LEV], ky = bly - P.c0[LEV], kz = blz - P.c0[LEV];
    a0 = 0.0f; a1 = 0.0f;
    unsigned lim = (unsigned)(K - 1);
    if ((unsigned)kx < lim && (unsigned)ky < lim && (unsigned)kz < lim) {
        int ib = P.base[LEV] + (kz * K + ky) * K + kx;
#pragma unroll
        for (int yz = 0; yz < 4; ++yz) {
            int id = ib + (yz >> 1) * K + (yz & 1) * K2;
            float wyz = fy[yz >> 1] * fz[yz & 1];
            acc_corner(s_dense[id], s_dense[id + 1], fx0 * wyz, fx1 * wyz,
                       a0, a1);
        }
    } else {
        // cold safety fallback: exact f32 hash gathers (corner outside box)
        const f2_t* tab = emb + (size_t)LEV * TABLE_SIZE;
#pragma unroll
        for (int k = 0; k < 8; ++k) {
            int bx = (k >> 2) & 1, by = (k >> 1) & 1, bz = k & 1;
            unsigned h = ((unsigned)(blx + bx)
                          ^ ((unsigned)(bly + by) * 2654435761u)
                          ^ ((unsigned)(blz + bz) * 805459861u)) & IDX_MASK;
            f2_t e = tab[h];
            float w = (bx ? wx : 1.0f - wx) * fy[by] * fz[bz];
            a0 += w * e.x; a1 += w * e.y;
        }
    }
}

// ---- pass 2: thread = point (grid-stride), all 16 levels serial, uniform
// path. LDS cut to 10.9 KB + fixed 2048-block grid -> 8 blocks/CU resident
// for the whole kernel (no R8 grid-quantization tail).
__global__ __launch_bounds__(256) void ingp_hash_v9(
    const float* __restrict__ x,
    const unsigned* __restrict__ tabAll,
    const unsigned* __restrict__ denseG,
    const f2_t* __restrict__ emb,
    float* __restrict__ out,
    Params P)
{
    __shared__ __align__(16) unsigned s_dense[N_LDS];
    {
        const uint4* src = (const uint4*)denseG;
        uint4* dst = (uint4*)s_dense;
        for (int id = threadIdx.x; id < N_LDS / 4; id += THREADS)
            dst[id] = src[id];
    }
    __syncthreads();

#pragma unroll 1
    for (int n = blockIdx.x * THREADS + (int)threadIdx.x; n < P.n_pts;
         n += GRID_BLOCKS * THREADS) {

        // one 16B x load (3 used floats; last point falls back to scalars)
        float xx, xy, xz;
        if (n < P.n_pts - 1) {
            f4_t v;
            __builtin_memcpy(&v, x + 3 * (size_t)n, 16);
            xx = v.x; xy = v.y; xz = v.z;
        } else {
            xx = x[3 * (size_t)n]; xy = x[3 * (size_t)n + 1]; xz = x[3 * (size_t)n + 2];
        }
        xx = fminf(fmaxf(xx, -1.0f), 1.0f);
        xy = fminf(fmaxf(xy, -1.0f), 1.0f);
        xz = fminf(fmaxf(xz, -1.0f), 1.0f);

        float* orow = out + (size_t)n * (N_LEVELS * 2);
        float a0, a1, b0, b1;

        // pair 0: L0, L1 from LDS
        eval_lds<0>(P, s_dense, emb, xx, xy, xz, a0, a1);
        eval_lds<1>(P, s_dense, emb, xx, xy, xz, b0, b1);
        { f4_t o = {a0, a1, b0, b1};
          __builtin_nontemporal_store(o, (f4_t*)(orow + 0)); }

        // pairs 1..7: L2..L15 hashed
#pragma unroll
        for (int p = 1; p < 8; ++p) {
            eval_hash(2.0f / P.res[2 * p], tabAll + (size_t)(2 * p) * TABLE_SIZE,
                      xx, xy, xz, a0, a1);
            eval_hash(2.0f / P.res[2 * p + 1], tabAll + (size_t)(2 * p + 1) * TABLE_SIZE,
                      xx, xy, xz, b0, b1);
            f4_t o = {a0, a1, b0, b1};
            __builtin_nontemporal_store(o, (f4_t*)(orow + p * 4));
        }
    }
}

// ---- fallback (ws unavailable): round-3 proven f32 pair kernel.
__global__ __launch_bounds__(256) void ingp_hash_pair_f32(
    const float* __restrict__ x, const f2_t* __restrict__ emb,
    float* __restrict__ out, int n_pts, Params P)
{
    int b = blockIdx.x;
    int slot = b & 7;
    int n = (b >> 3) * 256 + (int)threadIdx.x;
    if (n >= n_pts) return;
    float xx = fminf(fmaxf(x[n * 3 + 0], -1.0f), 1.0f);
    float xy = fminf(fmaxf(x[n * 3 + 1], -1.0f), 1.0f);
    float xz = fminf(fmaxf(x[n * 3 + 2], -1.0f), 1.0f);
    float r0 = 0.f, r1 = 0.f, r2 = 0.f, r3 = 0.f;
#pragma unroll
    for (int hl = 0; hl < 2; ++hl) {
        int lev = 2 * slot + hl;
        float grid = 2.0f / P.res[lev];
        int blx = (int)floorf((xx + 1.0f) / grid);
        int bly = (int)floorf((xy + 1.0f) / grid);
        int blz = (int)floorf((xz + 1.0f) / grid);
        float wx = (xx - ((float)blx * grid + -1.0f)) / grid;
        float wy = (xy - ((float)bly * grid + -1.0f)) / grid;
        float wz = (xz - ((float)blz * grid + -1.0f)) / grid;
        const f2_t* tab = emb + (size_t)lev * TABLE_SIZE;
        float acc0 = 0.0f, acc1 = 0.0f;
#pragma unroll
        for (int k = 0; k < 8; ++k) {
            int bx = (k >> 2) & 1, by = (k >> 1) & 1, bz = k & 1;
            unsigned h = ((unsigned)(blx + bx)
                          ^ ((unsigned)(bly + by) * 2654435761u)
                          ^ ((unsigned)(blz + bz) * 805459861u)) & IDX_MASK;
            f2_t e = tab[h];
            float w = (bx ? wx : 1.0f - wx) * (by ? wy : 1.0f - wy) * (bz ? wz : 1.0f - wz);
            acc0 += w * e.x; acc1 += w * e.y;
        }
        if (hl == 0) { r0 = acc0; r1 = acc1; } else { r2 = acc0; r3 = acc1; }
    }
    f4_t o4 = {r0, r1, r2, r3};
    __builtin_nontemporal_store(o4, (f4_t*)(out + (size_t)n * (N_LEVELS * 2) + slot * 4));
}

extern "C" void kernel_launch(void* const* d_in, const int* in_sizes, int n_in,
                              void* d_out, int out_size, void* d_ws, size_t ws_size,
                              hipStream_t stream) {
    const float* x   = (const float*)d_in[0];
    const float* emb = (const float*)d_in[1];
    float* out = (float*)d_out;
    int n_pts = in_sizes[0] / 3;

    Params P;
    // RESOLUTIONS: numpy float64 semantics on host (same libm as np)
    double b = exp((log(512.0) - log(16.0)) / 15.0);
    for (int i = 0; i < N_LEVELS; ++i)
        P.res[i] = (float)floor(16.0 * pow(b, (double)i));
    P.n_pts = n_pts;

    // Dense box bounds with the SAME fp32 ops the device uses (x in [0,1]).
    int base = 0;
    for (int l = 0; l < N_STAGED; ++l) {
        float grid = 2.0f / P.res[l];
        int blmin = (int)floorf(1.0f / grid);
        int blmax = (int)floorf(2.0f / grid);
        int K = blmax - blmin + 2;
        P.c0[l] = blmin; P.K[l] = K; P.K2[l] = K * K;
        P.base[l] = base;
        base += K * K * K;
        base = (base + 3) & ~3;        // 4-entry align each segment
    }
    P.base[N_STAGED] = base;

    size_t need = (size_t)N_LEVELS * TABLE_SIZE * 4 + (size_t)N_LDS * 4;
    bool ok = (base == N_LDS) && (ws_size >= need) && (d_ws != nullptr);
    if (ok) {
        unsigned* tabAll = (unsigned*)d_ws;
        unsigned* denseG = tabAll + (size_t)N_LEVELS * TABLE_SIZE;
        int nAll = N_LEVELS * TABLE_SIZE;
        hipLaunchKernelGGL(convert_all, dim3((nAll + 255) / 256), dim3(256), 0, stream,
                           (const f2_t*)emb, tabAll, nAll);
        hipLaunchKernelGGL(build_dense, dim3((base + 255) / 256), dim3(256), 0, stream,
                           (const f2_t*)emb, denseG, P);
        hipLaunchKernelGGL(ingp_hash_v9, dim3(GRID_BLOCKS), dim3(256), 0, stream,
                           x, tabAll, denseG, (const f2_t*)emb, out, P);
    } else {
        int blocks = 8 * ((n_pts + 255) / 256);
        hipLaunchKernelGGL(ingp_hash_pair_f32, dim3(blocks), dim3(256), 0, stream,
                           x, (const f2_t*)emb, out, n_pts, P);
    }
}